// Round 3
// baseline (98.798 us; speedup 1.0000x reference)
//
#include <hip/hip_runtime.h>
#include <math.h>

// Problem constants
#define NW 16384      // B*S words
#define Tt 16         // chars per word
#define Vv 262        // vocab
#define Hh 32         // GRU hidden per direction

// Packed G table: [2][262][16 m][8 slots] floats
//   slot 0..5 = (r_m, r_{m+16}, z_m, z_{m+16}, n_m, n_{m+16}), 6,7 pad
//   r,z slots include bih+bhh; n slots include bih only (bhh_n enters via MFMA C)
#define GROWF 8
#define GPERV (16*GROWF)        // 128 floats per vocab entry
#define GDIR  (Vv*GPERV)        // 33536 floats per dir
#define GFLOATS (2*GDIR)        // 67072
#define BHI_FOFF GFLOATS
#define BLO_FOFF (GFLOATS + 3072)

typedef float        f32x4  __attribute__((ext_vector_type(4)));
typedef short        bf16x8 __attribute__((ext_vector_type(8)));
typedef unsigned int u32;
typedef u32          u32x4  __attribute__((ext_vector_type(4)));
typedef int          i32x4  __attribute__((ext_vector_type(4)));

__device__ __forceinline__ unsigned short bf16_rtne(float f) {
    u32 u = __builtin_bit_cast(u32, f);
    u += 0x7fffu + ((u >> 16) & 1u);
    return (unsigned short)(u >> 16);
}
__device__ __forceinline__ u32 pk_bf16(float a, float b) {
    u32 r;
    asm("v_cvt_pk_bf16_f32 %0, %1, %2" : "=v"(r) : "v"(a), "v"(b));
    return r;
}
__device__ __forceinline__ float fsigm(float x) {
    return __builtin_amdgcn_rcpf(1.0f + __expf(-x));
}
__device__ __forceinline__ float ftanh(float x) {
    return 1.0f - 2.0f * __builtin_amdgcn_rcpf(1.0f + __expf(2.0f * x));
}

// ---------------------------------------------------------------------------
// Precompute. Blocks 0..261: packed G table. Blocks 262..264: Whh -> bf16
// hi/lo B-fragments (identical layout to round 2, verified correct).
// ---------------------------------------------------------------------------
__global__ __launch_bounds__(256) void precomp(
    const float* __restrict__ emb,
    const float* __restrict__ Wih_f, const float* __restrict__ Whh_f,
    const float* __restrict__ bih_f, const float* __restrict__ bhh_f,
    const float* __restrict__ Wih_b, const float* __restrict__ Whh_b,
    const float* __restrict__ bih_b, const float* __restrict__ bhh_b,
    float* __restrict__ ws)
{
    int b = blockIdx.x;
    if (b < 262) {
        int idx = b * 256 + threadIdx.x;      // < 67072 exactly
        int dir = idx / GDIR;
        int rem = idx - dir * GDIR;
        int v   = rem / GPERV;
        int r2  = rem - v * GPERV;
        int m   = r2 >> 3;
        int slot= r2 & 7;
        float val = 0.0f;
        if (slot < 6) {
            int g = m + (slot & 1) * 16 + (slot >> 1) * 32;
            const float* Wih = dir ? Wih_b : Wih_f;
            float acc = (dir ? bih_b : bih_f)[g];
            if (slot < 4) acc += (dir ? bhh_b : bhh_f)[g];  // fold bhh for r,z only
            const f32x4* er = (const f32x4*)(emb + v * 64);
            const f32x4* wr = (const f32x4*)(Wih + g * 64);
            float s = 0.0f;
            #pragma unroll
            for (int e = 0; e < 16; ++e) {
                f32x4 a = er[e], w = wr[e];
                s = fmaf(a[0], w[0], s);
                s = fmaf(a[1], w[1], s);
                s = fmaf(a[2], w[2], s);
                s = fmaf(a[3], w[3], s);
            }
            val = acc + s;
        }
        ws[idx] = val;
    } else {
        int t = (b - 262) * 256 + threadIdx.x;
        if (t >= 768) return;
        int dir = t / 384;
        int r2  = t - dir * 384;
        int c   = r2 >> 6;          // unit chunk 0..5
        int l   = r2 & 63;          // lane
        int m   = l & 15, q = l >> 4;
        const float* Whh = dir ? Whh_b : Whh_f;
        const float* row = Whh + (16 * c + m) * Hh + 8 * q;
        u32 hiw[4], low[4];
        #pragma unroll
        for (int p = 0; p < 4; ++p) {
            float f0 = row[2 * p], f1 = row[2 * p + 1];
            unsigned short h0 = bf16_rtne(f0), h1 = bf16_rtne(f1);
            float rr0 = f0 - __builtin_bit_cast(float, (u32)h0 << 16);
            float rr1 = f1 - __builtin_bit_cast(float, (u32)h1 << 16);
            unsigned short l0 = bf16_rtne(rr0), l1 = bf16_rtne(rr1);
            hiw[p] = (u32)h0 | ((u32)h1 << 16);
            low[p] = (u32)l0 | ((u32)l1 << 16);
        }
        u32x4* dh = (u32x4*)(ws + BHI_FOFF) + (dir * 6 + c) * 64 + l;
        u32x4* dl = (u32x4*)(ws + BLO_FOFF) + (dir * 6 + c) * 64 + l;
        u32x4 vh = {hiw[0], hiw[1], hiw[2], hiw[3]};
        u32x4 vl = {low[0], low[1], low[2], low[3]};
        *dh = vh;
        *dl = vl;
    }
}

// ---------------------------------------------------------------------------
// Main: one wave = (16 words, 1 dir). 16x16x32 bf16 MFMA, hi/lo split.
// gi(t+1) prefetched into ping-ponged GA/GB register sets (vector dwordx4
// loads from packed table). LDS transpose stride 36 -> ds_read_b128.
// ---------------------------------------------------------------------------
__global__ __launch_bounds__(256, 2) void gru_main(
    const int*   __restrict__ x,
    const float* __restrict__ ws,
    const float* __restrict__ bhh_f,
    const float* __restrict__ bhh_b,
    float*       __restrict__ out)
{
    __shared__ float hbuf[4][16 * 36];   // per-wave transpose buffer (b128-aligned reads)
    __shared__ int   chs[4][16 * 17];    // per-wave char staging

    const int tid  = threadIdx.x;
    const int lane = tid & 63;
    const int widx = tid >> 6;
    const int wave = blockIdx.x * 4 + widx;
    const int dir  = wave & 1;
    const int wg   = wave >> 1;
    const int m = lane & 15, q = lane >> 4;

    // stage this wave's 16 words x 16 chars
    {
        i32x4 cv = *(const i32x4*)(x + wg * 256 + lane * 4);
        #pragma unroll
        for (int j2 = 0; j2 < 4; ++j2) {
            int p = lane * 4 + j2;
            chs[widx][(p >> 4) * 17 + (p & 15)] = cv[j2];
        }
    }

    // Whh B-fragments (hi/lo)
    bf16x8 bhi[6], blo[6];
    {
        const u32x4* ph = (const u32x4*)(ws + BHI_FOFF) + dir * 384 + lane;
        const u32x4* pl = (const u32x4*)(ws + BLO_FOFF) + dir * 384 + lane;
        #pragma unroll
        for (int c = 0; c < 6; ++c) {
            bhi[c] = __builtin_bit_cast(bf16x8, ph[c * 64]);
            blo[c] = __builtin_bit_cast(bf16x8, pl[c * 64]);
        }
    }
    const float* bhh = dir ? bhh_b : bhh_f;
    const float bn0 = bhh[64 + m];
    const float bn1 = bhh[80 + m];
    const f32x4 an0c = {bn0, bn0, bn0, bn0};
    const f32x4 an1c = {bn1, bn1, bn1, bn1};
    const float* Gt = ws + dir * GDIR;

    f32x4 h0v = {0.f, 0.f, 0.f, 0.f};
    f32x4 h1v = {0.f, 0.f, 0.f, 0.f};
    f32x4 mx0 = {-3e38f, -3e38f, -3e38f, -3e38f};
    f32x4 mx1 = {-3e38f, -3e38f, -3e38f, -3e38f};

    float* hb = hbuf[widx];
    int*   ch = chs[widx];
    const int t0 = dir ? 15 : 0;
    const int sg = dir ? -1 : 1;

    int ca[4];                            // chars for the NEXT gi prefetch
    f32x4 GA[8], GB[8];                   // gi ping-pong: [2r]=(r,r',z,z'), [2r+1]=(n,n',0,0)

    auto gload = [&](f32x4 (&Gv)[8]) {
        #pragma unroll
        for (int r = 0; r < 4; ++r) {
            const f32x4* gp = (const f32x4*)(Gt + ca[r] * GPERV + m * GROWF);
            Gv[2 * r]     = gp[0];
            Gv[2 * r + 1] = gp[1];
        }
    };
    auto gates = [&](const f32x4& ar0, const f32x4& ar1,
                     const f32x4& az0, const f32x4& az1,
                     const f32x4& an0, const f32x4& an1,
                     const f32x4 (&Gc)[8]) {
        #pragma unroll
        for (int r = 0; r < 4; ++r) {
            float gn0 = Gc[2 * r + 1][0];
            float gn1 = Gc[2 * r + 1][1];
            float rr0 = fsigm(ar0[r]);
            float zz0 = fsigm(az0[r]);
            float nn0 = ftanh(fmaf(rr0, an0[r], gn0));
            float hx0 = nn0 + zz0 * (h0v[r] - nn0);
            mx0[r] = fmaxf(mx0[r], hx0);
            h0v[r] = hx0;
            hb[(4 * q + r) * 36 + m] = hx0;

            float rr1 = fsigm(ar1[r]);
            float zz1 = fsigm(az1[r]);
            float nn1 = ftanh(fmaf(rr1, an1[r], gn1));
            float hx1 = nn1 + zz1 * (h1v[r] - nn1);
            mx1[r] = fmaxf(mx1[r], hx1);
            h1v[r] = hx1;
            hb[(4 * q + r) * 36 + 16 + m] = hx1;
        }
    };

#define TRIPLE(acc, c) \
    acc = __builtin_amdgcn_mfma_f32_16x16x32_bf16(Alo, bhi[c], acc, 0, 0, 0); \
    acc = __builtin_amdgcn_mfma_f32_16x16x32_bf16(Ahi, blo[c], acc, 0, 0, 0); \
    acc = __builtin_amdgcn_mfma_f32_16x16x32_bf16(Ahi, bhi[c], acc, 0, 0, 0);

    auto step = [&](const f32x4 (&Gc)[8], f32x4 (&Gn)[8], int t) {
        if (t < 15) gload(Gn);                       // prefetch gi(t+1)
        if (t < 14) {                                // prefetch chars(t+2)
            int s2 = t0 + (t + 2) * sg;
            #pragma unroll
            for (int r = 0; r < 4; ++r) ca[r] = ch[(4 * q + r) * 17 + s2];
        }
        // transpose read: h[word m][units 8q..8q+7]
        const f32x4 A0 = *(const f32x4*)(hb + m * 36 + 8 * q);
        const f32x4 A1 = *(const f32x4*)(hb + m * 36 + 8 * q + 4);
        // bf16 hi/lo split
        u32 w0 = pk_bf16(A0[0], A0[1]), w1 = pk_bf16(A0[2], A0[3]);
        u32 w2 = pk_bf16(A1[0], A1[1]), w3 = pk_bf16(A1[2], A1[3]);
        float e0 = __builtin_bit_cast(float, w0 << 16);
        float o0 = __builtin_bit_cast(float, w0 & 0xffff0000u);
        float e1 = __builtin_bit_cast(float, w1 << 16);
        float o1 = __builtin_bit_cast(float, w1 & 0xffff0000u);
        float e2 = __builtin_bit_cast(float, w2 << 16);
        float o2 = __builtin_bit_cast(float, w2 & 0xffff0000u);
        float e3 = __builtin_bit_cast(float, w3 << 16);
        float o3 = __builtin_bit_cast(float, w3 & 0xffff0000u);
        u32 v0 = pk_bf16(A0[0] - e0, A0[1] - o0);
        u32 v1 = pk_bf16(A0[2] - e1, A0[3] - o1);
        u32 v2 = pk_bf16(A1[0] - e2, A1[1] - o2);
        u32 v3 = pk_bf16(A1[2] - e3, A1[3] - o3);
        u32x4 hiq = {w0, w1, w2, w3};
        u32x4 loq = {v0, v1, v2, v3};
        bf16x8 Ahi = __builtin_bit_cast(bf16x8, hiq);
        bf16x8 Alo = __builtin_bit_cast(bf16x8, loq);

        f32x4 ar0 = {Gc[0][0], Gc[2][0], Gc[4][0], Gc[6][0]};
        f32x4 ar1 = {Gc[0][1], Gc[2][1], Gc[4][1], Gc[6][1]};
        f32x4 az0 = {Gc[0][2], Gc[2][2], Gc[4][2], Gc[6][2]};
        f32x4 az1 = {Gc[0][3], Gc[2][3], Gc[4][3], Gc[6][3]};
        f32x4 an0 = an0c, an1 = an1c;
        TRIPLE(ar0, 0)
        TRIPLE(ar1, 1)
        TRIPLE(az0, 2)
        TRIPLE(az1, 3)
        TRIPLE(an0, 4)
        TRIPLE(an1, 5)
        gates(ar0, ar1, az0, az1, an0, an1, Gc);
    };

    // prologue: gi(0) -> GA, chars(1) -> ca
    #pragma unroll
    for (int r = 0; r < 4; ++r) ca[r] = ch[(4 * q + r) * 17 + t0];
    gload(GA);
    #pragma unroll
    for (int r = 0; r < 4; ++r) ca[r] = ch[(4 * q + r) * 17 + t0 + sg];

    // step 0: h=0 -> gh=0, no transpose/MFMA; also prefetch gi(1), chars(2)
    gload(GB);
    #pragma unroll
    for (int r = 0; r < 4; ++r) ca[r] = ch[(4 * q + r) * 17 + t0 + 2 * sg];
    {
        f32x4 ar0 = {GA[0][0], GA[2][0], GA[4][0], GA[6][0]};
        f32x4 ar1 = {GA[0][1], GA[2][1], GA[4][1], GA[6][1]};
        f32x4 az0 = {GA[0][2], GA[2][2], GA[4][2], GA[6][2]};
        f32x4 az1 = {GA[0][3], GA[2][3], GA[4][3], GA[6][3]};
        gates(ar0, ar1, az0, az1, an0c, an1c, GA);
    }

    // steps 1..15 with GA/GB ping-pong
    step(GB, GA, 1);
    #pragma unroll 1
    for (int it = 0; it < 7; ++it) {
        step(GA, GB, 2 + 2 * it);
        step(GB, GA, 3 + 2 * it);
    }
#undef TRIPLE

    // store: out[word][dir*32 + unit]
    const int ob = wg * 16 * 64 + dir * 32;
    #pragma unroll
    for (int r = 0; r < 4; ++r) {
        out[ob + (4 * q + r) * 64 + m]      = mx0[r];
        out[ob + (4 * q + r) * 64 + 16 + m] = mx1[r];
    }
}

extern "C" void kernel_launch(void* const* d_in, const int* in_sizes, int n_in,
                              void* d_out, int out_size, void* d_ws, size_t ws_size,
                              hipStream_t stream) {
    const int*   x     = (const int*)  d_in[0];
    const float* emb   = (const float*)d_in[1];
    const float* Wih_f = (const float*)d_in[2];
    const float* Whh_f = (const float*)d_in[3];
    const float* bih_f = (const float*)d_in[4];
    const float* bhh_f = (const float*)d_in[5];
    const float* Wih_b = (const float*)d_in[6];
    const float* Whh_b = (const float*)d_in[7];
    const float* bih_b = (const float*)d_in[8];
    const float* bhh_b = (const float*)d_in[9];
    float* out = (float*)d_out;
    float* ws  = (float*)d_ws;

    precomp<<<265, 256, 0, stream>>>(emb, Wih_f, Whh_f, bih_f, bhh_f,
                                     Wih_b, Whh_b, bih_b, bhh_b, ws);
    gru_main<<<512, 256, 0, stream>>>(x, ws, bhh_f, bhh_b, out);
}